// Round 16
// baseline (1220.988 us; speedup 1.0000x reference)
//
#include <hip/hip_runtime.h>
#include <cmath>

typedef __bf16 bf16;
typedef bf16 bf16x4 __attribute__((ext_vector_type(4)));
typedef bf16 bf16x8 __attribute__((ext_vector_type(8)));
typedef float f32x4 __attribute__((ext_vector_type(4)));

#define T_TOK 16384
#define HD 1024
#define ID 4096
#define MAXR 51200          // 16384 shared + 32768 routed + 8*256 align pad

// ---------------- async global -> LDS (16B per lane, lds dest wave-uniform) ----------------
__device__ __forceinline__ void async16(const void* g, void* l) {
  void* gp = (void*)g;  // drop const
  __builtin_amdgcn_global_load_lds((__attribute__((address_space(1))) void*)gp,
                                   (__attribute__((address_space(3))) void*)l,
                                   16, 0, 0);
}

// ------- fused cast X->bf16 + router (16 tokens/block, 1024 thr; NO atomics) -------
__global__ __launch_bounds__(1024)
void cast_router_kernel(const float* __restrict__ X, const float* __restrict__ Wr,
                        bf16* __restrict__ Xb, int* __restrict__ topk_idx,
                        float* __restrict__ topk_w) {
  __shared__ float W[1024 * 9];  // pad stride 9 to dodge bank conflicts
  for (int i = threadIdx.x; i < 1024 * 8; i += 1024)
    W[(i >> 3) * 9 + (i & 7)] = Wr[i];
  __syncthreads();
  const int wave = threadIdx.x >> 6, lane = threadIdx.x & 63;
  const int t = blockIdx.x * 16 + wave;
  const float* xr = X + (size_t)t * HD;
  bf16* xb = Xb + (size_t)t * HD;
  float acc[8] = {0.f, 0.f, 0.f, 0.f, 0.f, 0.f, 0.f, 0.f};
#pragma unroll
  for (int j = 0; j < 4; ++j) {
    const int base = lane * 4 + j * 256;
    const float4 v = *(const float4*)(xr + base);
    bf16x4 o;
    o.x = (bf16)v.x; o.y = (bf16)v.y; o.z = (bf16)v.z; o.w = (bf16)v.w;
    *(bf16x4*)(xb + base) = o;
    const float xv[4] = {v.x, v.y, v.z, v.w};
#pragma unroll
    for (int c = 0; c < 4; ++c) {
      const float* wp = &W[(base + c) * 9];
#pragma unroll
      for (int e2 = 0; e2 < 8; ++e2) acc[e2] += xv[c] * wp[e2];
    }
  }
#pragma unroll
  for (int off = 32; off; off >>= 1)
#pragma unroll
    for (int e2 = 0; e2 < 8; ++e2) acc[e2] += __shfl_down(acc[e2], off);
  if (lane == 0) {
    int i0 = 0; float m0 = acc[0];
#pragma unroll
    for (int e2 = 1; e2 < 8; ++e2) if (acc[e2] > m0) { m0 = acc[e2]; i0 = e2; }
    int i1 = -1; float m1 = -3.4e38f;
#pragma unroll
    for (int e2 = 0; e2 < 8; ++e2)
      if (e2 != i0 && acc[e2] > m1) { m1 = acc[e2]; i1 = e2; }
    // renormalized top-2 softmax weights: p0/(p0+p1) = sigmoid(l0-l1)
    const float w0 = 1.f / (1.f + __expf(m1 - m0));
    topk_idx[2 * t] = i0;  topk_idx[2 * t + 1] = i1;
    topk_w[2 * t] = w0;    topk_w[2 * t + 1] = 1.f - w0;
  }
}

// ------------- transpose + cast weights: [9][R][C] f32 -> [9][C][R] bf16 -------------
__global__ __launch_bounds__(256)
void transpose_cast(const float* __restrict__ srcR, const float* __restrict__ srcS,
                    bf16* __restrict__ dst, int R, int C) {
  const int e = blockIdx.z;
  const float* src = (e < 8) ? srcR + (size_t)e * R * C : srcS;
  __shared__ float tile[64][65];
  const int c0 = blockIdx.x * 64, r0 = blockIdx.y * 64;
  const int tx = threadIdx.x & 15;   // float4 col group
  const int ty = threadIdx.x >> 4;   // row 0..15
#pragma unroll
  for (int i = 0; i < 64; i += 16) {
    const float4 v = *(const float4*)(src + (size_t)(r0 + ty + i) * C + c0 + tx * 4);
    tile[ty + i][tx * 4 + 0] = v.x;
    tile[ty + i][tx * 4 + 1] = v.y;
    tile[ty + i][tx * 4 + 2] = v.z;
    tile[ty + i][tx * 4 + 3] = v.w;
  }
  __syncthreads();
  bf16* d = dst + (size_t)e * R * C;
#pragma unroll
  for (int i = 0; i < 64; i += 16) {
    const int col = ty + i;          // src col = dst row
    bf16x4 o;
    o.x = (bf16)tile[tx * 4 + 0][col];
    o.y = (bf16)tile[tx * 4 + 1][col];
    o.z = (bf16)tile[tx * 4 + 2][col];
    o.w = (bf16)tile[tx * 4 + 3][col];
    *(bf16x4*)(d + (size_t)(c0 + col) * R + r0 + tx * 4) = o;
  }
}

// ------- stable scatter into 256-aligned per-expert segments; block 8 = shared seg -------
__global__ __launch_bounds__(1024)
void scatter_kernel(const int* __restrict__ topk_idx, const float* __restrict__ topk_w,
                    int* __restrict__ row_token, float* __restrict__ row_w,
                    int* __restrict__ row_exp, int* __restrict__ token_rows,
                    int* __restrict__ meta) {
  const int e = blockIdx.x;
  const int tid = threadIdx.x;
  const int wv = tid >> 6, ln = tid & 63;
  __shared__ int whist[16][8];
  __shared__ int hist[8];

  int lc0 = 0, lc1 = 0, lc2 = 0, lc3 = 0, lc4 = 0, lc5 = 0, lc6 = 0, lc7 = 0;
  for (int t = tid; t < T_TOK; t += 1024) {
    const int i0 = topk_idx[2 * t], i1 = topk_idx[2 * t + 1];
    lc0 += (i0 == 0) + (i1 == 0);  lc1 += (i0 == 1) + (i1 == 1);
    lc2 += (i0 == 2) + (i1 == 2);  lc3 += (i0 == 3) + (i1 == 3);
    lc4 += (i0 == 4) + (i1 == 4);  lc5 += (i0 == 5) + (i1 == 5);
    lc6 += (i0 == 6) + (i1 == 6);  lc7 += (i0 == 7) + (i1 == 7);
  }
#pragma unroll
  for (int off = 32; off; off >>= 1) {
    lc0 += __shfl_down(lc0, off); lc1 += __shfl_down(lc1, off);
    lc2 += __shfl_down(lc2, off); lc3 += __shfl_down(lc3, off);
    lc4 += __shfl_down(lc4, off); lc5 += __shfl_down(lc5, off);
    lc6 += __shfl_down(lc6, off); lc7 += __shfl_down(lc7, off);
  }
  if (ln == 0) {
    whist[wv][0] = lc0; whist[wv][1] = lc1; whist[wv][2] = lc2; whist[wv][3] = lc3;
    whist[wv][4] = lc4; whist[wv][5] = lc5; whist[wv][6] = lc6; whist[wv][7] = lc7;
  }
  __syncthreads();
  if (tid < 8) {
    int s = 0;
#pragma unroll
    for (int w = 0; w < 16; ++w) s += whist[w][tid];
    hist[tid] = s;
  }
  __syncthreads();

  if (e == 8) {  // shared-expert segment: rows [0,16384), weight 1
    for (int r = tid; r < T_TOK; r += 1024) {
      row_token[r] = r; row_w[r] = 1.f; row_exp[r] = 8;
    }
    if (tid == 0) {
      int tot = T_TOK;
      for (int i = 0; i < 8; ++i) tot += (hist[i] + 255) & ~255;
      meta[0] = tot;
    }
    return;
  }

  int base = T_TOK;
  for (int i = 0; i < e; ++i) base += (hist[i] + 255) & ~255;
  const int cnt = hist[e];
  const int pc = (cnt + 255) & ~255;

  __shared__ int wsum[16];
  int written = 0;
  for (int c = 0; c < T_TOK / 1024; ++c) {
    const int t = c * 1024 + tid;
    const int i0 = topk_idx[2 * t], i1 = topk_idx[2 * t + 1];
    const int slot = (i0 == e) ? 0 : ((i1 == e) ? 1 : -1);
    const unsigned long long m = __ballot(slot >= 0);
    if (ln == 0) wsum[wv] = (int)__popcll(m);
    __syncthreads();
    int off = written;
    for (int i = 0; i < wv; ++i) off += wsum[i];
    if (slot >= 0) {
      const int rank = (int)__popcll(m & ((1ULL << ln) - 1ULL));  // exclusive in-wave
      const int pos = base + off + rank;
      row_token[pos] = t;
      row_w[pos] = topk_w[2 * t + slot];
      row_exp[pos] = e;
      token_rows[2 * t + slot] = pos;  // inverse map for the combine pass
    }
    int tot = 0;
#pragma unroll
    for (int i = 0; i < 16; ++i) tot += wsum[i];
    written += tot;
    __syncthreads();  // wsum reused next chunk
  }
  for (int p = written + tid; p < pc; p += 1024) {  // padding rows
    row_token[base + p] = 0; row_w[base + p] = 0.f; row_exp[base + p] = e;
  }
}

// ============ UP GEMM, 128x256 tile, BK=32, 8 waves, triple-buffered ============
// Geometry matched to gemm_dn: 73.7 KB LDS + ~92 VGPR -> 2 blocks/CU. Cross-block
// overlap hides the per-tile vmcnt+barrier drain (the 1-block/CU 256^2 tile could
// not). A gathered via row_token; counted vmcnt(3); silu -> act bf16 NT store.
__global__ __launch_bounds__(512)
void gemm_up(const bf16* __restrict__ A0, const bf16* __restrict__ WT,
             bf16* __restrict__ bout, const int* __restrict__ row_token,
             const int* __restrict__ row_exp, const int* __restrict__ meta,
             int chunk_base) {
  constexpr int NDIM = ID, KDIM = HD;
  constexpr int NT = KDIM / 32;  // 32
  const int total = meta[0];

  const int gx = gridDim.x;
  const int nwg = gx * gridDim.y;
  int id = blockIdx.y * gx + blockIdx.x;
  {
    const int q = nwg >> 3, rm = nwg & 7;
    const int xcd = id & 7, loc = id >> 3;
    id = (xcd < rm ? xcd * (q + 1) : rm * (q + 1) + (xcd - rm) * q) + loc;
  }
  const int bx = id % gx, by = id / gx;

  const int r0 = chunk_base + by * 128;   // 128-row tiles; segments are 256-aligned
  if (r0 >= total) return;
  const int n0 = bx * 256;

  __shared__ __align__(16) char lds[3 * 24576];  // 3 bufs x (A 8K + B 16K)

  const int tid = threadIdx.x;
  const int wid = tid >> 6, lane = tid & 63;
  const int e = row_exp[r0];
  const bf16* W = WT + (size_t)e * NDIM * KDIM;

  // stage units: A rows 0..127 (gathered); B rows 0..127; B rows 128..255
  const int tr = tid >> 2;
  const int tb = tid & 3;
  const int bl = tb ^ ((tr >> 1) & 3);   // ((tr+128)>>1)&3 == (tr>>1)&3: same for B1
  const bf16* gA  = A0 + (size_t)row_token[r0 + tr] * KDIM + bl * 8;
  const bf16* gB0 = W + (size_t)(n0 + tr) * KDIM + bl * 8;
  const bf16* gB1 = W + (size_t)(n0 + 128 + tr) * KDIM + bl * 8;
  char* const ldsb = lds;
  const int wo = wid * 1024;

#define USTAGE_A(c, kt)  async16(gA  + (kt) * 32, ldsb + (c) * 24576 + wo)
#define USTAGE_B0(c, kt) async16(gB0 + (kt) * 32, ldsb + (c) * 24576 + 8192 + wo)
#define USTAGE_B1(c, kt) async16(gB1 + (kt) * 32, ldsb + (c) * 24576 + 16384 + wo)

  const int l15 = lane & 15, kg = lane >> 4;
  const int wr = wid >> 2, wc = wid & 3;  // wave grid 2(M) x 4(N); per-wave 64x64 out
  int offA[4], offB[4];
#pragma unroll
  for (int m = 0; m < 4; ++m) {
    const int row = wr * 64 + m * 16 + l15;
    offA[m] = row * 64 + ((kg ^ ((row >> 1) & 3)) << 4);
  }
#pragma unroll
  for (int n = 0; n < 4; ++n) {
    const int row = wc * 64 + n * 16 + l15;
    offB[n] = 8192 + row * 64 + ((kg ^ ((row >> 1) & 3)) << 4);
  }

  f32x4 acc[4][4] = {};

  USTAGE_A(0, 0); USTAGE_B0(0, 0); USTAGE_B1(0, 0);
  USTAGE_A(1, 1); USTAGE_B0(1, 1); USTAGE_B1(1, 1);

  int cb = 0, cn = 2;
  for (int kt = 0; kt < NT; ++kt) {
    if (kt + 1 < NT) asm volatile("s_waitcnt vmcnt(3)" ::: "memory");
    else             asm volatile("s_waitcnt vmcnt(0)" ::: "memory");
    __builtin_amdgcn_s_barrier();
    asm volatile("" ::: "memory");
    __builtin_amdgcn_sched_barrier(0);
    const char* Tb = ldsb + cb * 24576;
    const bool pf = (kt + 2 < NT);
    const int k2 = kt + 2;
    bf16x8 bfr[4];
#pragma unroll
    for (int q = 0; q < 4; ++q) {
      if (pf) {
        if (q == 0)      USTAGE_A(cn, k2);
        else if (q == 1) USTAGE_B0(cn, k2);
        else if (q == 2) USTAGE_B1(cn, k2);
      }
      if (q == 0) {
#pragma unroll
        for (int n = 0; n < 4; ++n) bfr[n] = *(const bf16x8*)(Tb + offB[n]);
      }
      const bf16x8 a0 = *(const bf16x8*)(Tb + offA[q]);
      __builtin_amdgcn_s_setprio(1);
#pragma unroll
      for (int n = 0; n < 4; ++n)
        acc[q][n] = __builtin_amdgcn_mfma_f32_16x16x32_bf16(a0, bfr[n], acc[q][n], 0, 0, 0);
      __builtin_amdgcn_s_setprio(0);
    }
    cb = (cb == 2) ? 0 : cb + 1;
    cn = (cn == 2) ? 0 : cn + 1;
  }
#undef USTAGE_A
#undef USTAGE_B0
#undef USTAGE_B1

  // epilogue: silu -> act (local rows). D layout (m89): col=lane&15, row=(lane>>4)*4+reg
  const int orow = wr * 64;
  const int ocol = n0 + wc * 64;
#pragma unroll
  for (int m = 0; m < 4; ++m) {
#pragma unroll
    for (int rr = 0; rr < 4; ++rr) {
      const int row = (r0 - chunk_base) + orow + m * 16 + kg * 4 + rr;
      bf16* p = bout + (size_t)row * NDIM + ocol + l15;
#pragma unroll
      for (int n = 0; n < 4; ++n) {
        const float x = acc[m][n][rr];
        __builtin_nontemporal_store((bf16)(x / (1.f + __expf(-x))), &p[n * 16]);
      }
    }
  }
}

// ============ DOWN GEMM, 128x256 tile, BK=32, 8 waves, triple-buffered ============
__global__ __launch_bounds__(512)
void gemm_dn(const bf16* __restrict__ A0, const bf16* __restrict__ WT,
             bf16* __restrict__ bout, float* __restrict__ out,
             const int* __restrict__ row_token, const float* __restrict__ row_w,
             const int* __restrict__ row_exp, const int* __restrict__ meta,
             int chunk_base) {
  constexpr int KDIM = ID;
  constexpr int NT = KDIM / 32;  // 128
  const int total = meta[0];

  const int gx = gridDim.x;
  const int nwg = gx * gridDim.y;
  int id = blockIdx.y * gx + blockIdx.x;
  {
    const int q = nwg >> 3, rm = nwg & 7;
    const int xcd = id & 7, loc = id >> 3;
    id = (xcd < rm ? xcd * (q + 1) : rm * (q + 1) + (xcd - rm) * q) + loc;
  }
  const int bx = id % gx, by = id / gx;

  const int r0 = chunk_base + by * 128;   // 128-row tiles; segments are 256-aligned
  if (r0 >= total) return;
  const int n0 = bx * 256;

  __shared__ __align__(16) char lds[3 * 24576];  // 3 bufs x (A 8K + B 16K)

  const int tid = threadIdx.x;
  const int wid = tid >> 6, lane = tid & 63;
  const int e = row_exp[r0];
  const bf16* W = WT + (size_t)e * HD * KDIM;

  // stage units: A rows 0..127; B rows 0..127; B rows 128..255
  const int tr = tid >> 2;
  const int tb = tid & 3;
  const int bl = tb ^ ((tr >> 1) & 3);   // ((tr+128)>>1)&3 == (tr>>1)&3: same for B1
  const bf16* gA  = A0 + (size_t)(r0 - chunk_base + tr) * KDIM + bl * 8;
  const bf16* gB0 = W + (size_t)(n0 + tr) * KDIM + bl * 8;
  const bf16* gB1 = W + (size_t)(n0 + 128 + tr) * KDIM + bl * 8;
  char* const ldsb = lds;
  const int wo = wid * 1024;

#define DSTAGE_A(c, kt)  async16(gA  + (kt) * 32, ldsb + (c) * 24576 + wo)
#define DSTAGE_B0(c, kt) async16(gB0 + (kt) * 32, ldsb + (c) * 24576 + 8192 + wo)
#define DSTAGE_B1(c, kt) async16(gB1 + (kt) * 32, ldsb + (c) * 24576 + 16384 + wo)

  const int l15 = lane & 15, kg = lane >> 4;
  const int wr = wid >> 2, wc = wid & 3;  // wave grid 2(M) x 4(N); per-wave 64x64 out
  int offA[4], offB[4];
#pragma unroll
  for (int m = 0; m < 4; ++m) {
    const int row = wr * 64 + m * 16 + l15;
    offA[m] = row * 64 + ((kg ^ ((row >> 1) & 3)) << 4);
  }
#pragma unroll
  for (int n = 0; n < 4; ++n) {
    const int row = wc * 64 + n * 16 + l15;
    offB[n] = 8192 + row * 64 + ((kg ^ ((row >> 1) & 3)) << 4);
  }

  f32x4 acc[4][4] = {};

  DSTAGE_A(0, 0); DSTAGE_B0(0, 0); DSTAGE_B1(0, 0);
  DSTAGE_A(1, 1); DSTAGE_B0(1, 1); DSTAGE_B1(1, 1);

  int cb = 0, cn = 2;
  for (int kt = 0; kt < NT; ++kt) {
    if (kt + 1 < NT) asm volatile("s_waitcnt vmcnt(3)" ::: "memory");
    else             asm volatile("s_waitcnt vmcnt(0)" ::: "memory");
    __builtin_amdgcn_s_barrier();
    asm volatile("" ::: "memory");
    __builtin_amdgcn_sched_barrier(0);
    const char* Tb = ldsb + cb * 24576;
    const bool pf = (kt + 2 < NT);
    const int k2 = kt + 2;
    bf16x8 bfr[4];
#pragma unroll
    for (int q = 0; q < 4; ++q) {
      if (pf) {
        if (q == 0)      DSTAGE_A(cn, k2);
        else if (q == 1) DSTAGE_B0(cn, k2);
        else if (q == 2) DSTAGE_B1(cn, k2);
      }
      if (q == 0) {
#pragma unroll
        for (int n = 0; n < 4; ++n) bfr[n] = *(const bf16x8*)(Tb + offB[n]);
      }
      const bf16x8 a0 = *(const bf16x8*)(Tb + offA[q]);
      __builtin_amdgcn_s_setprio(1);
#pragma unroll
      for (int n = 0; n < 4; ++n)
        acc[q][n] = __builtin_amdgcn_mfma_f32_16x16x32_bf16(a0, bfr[n], acc[q][n], 0, 0, 0);
      __builtin_amdgcn_s_setprio(0);
    }
    cb = (cb == 2) ? 0 : cb + 1;
    cn = (cn == 2) ? 0 : cn + 1;
  }
#undef DSTAGE_A
#undef DSTAGE_B0
#undef DSTAGE_B1

  // epilogue. D layout (m89): col = lane&15, row = (lane>>4)*4 + reg
  const int orow = wr * 64;
  const int ocol = n0 + wc * 64;
  if (e == 8) {
#pragma unroll
    for (int m = 0; m < 4; ++m) {
#pragma unroll
      for (int rr = 0; rr < 4; ++rr) {
        const int row = r0 + orow + m * 16 + kg * 4 + rr;
        const int tok = row_token[row];
        float* p = out + (size_t)tok * HD + ocol + l15;
#pragma unroll
        for (int n = 0; n < 4; ++n) p[n * 16] = acc[m][n][rr];
      }
    }
  } else {
#pragma unroll
    for (int m = 0; m < 4; ++m) {
#pragma unroll
      for (int rr = 0; rr < 4; ++rr) {
        const int row = r0 + orow + m * 16 + kg * 4 + rr;
        const float w = row_w[row];
        bf16* p = bout + (size_t)(row - T_TOK) * HD + ocol + l15;
#pragma unroll
        for (int n = 0; n < 4; ++n)
          __builtin_nontemporal_store((bf16)(w * acc[m][n][rr]), &p[n * 16]);
      }
    }
  }
}

// -------- combine: out[t] += routed_out[rowA(t)] + routed_out[rowB(t)] (grid-stride) --------
__global__ __launch_bounds__(256)
void combine_kernel(float* __restrict__ out, const bf16* __restrict__ routed_out,
                    const int* __restrict__ token_rows) {
  const int i = (threadIdx.x & 255) * 4;
  for (int t = blockIdx.x; t < T_TOK; t += gridDim.x) {
    const int rA = token_rows[2 * t] - T_TOK;
    const int rB = token_rows[2 * t + 1] - T_TOK;
    float4 o = *(const float4*)(out + (size_t)t * HD + i);
    const bf16x4 a = *(const bf16x4*)(routed_out + (size_t)rA * HD + i);
    const bf16x4 b = *(const bf16x4*)(routed_out + (size_t)rB * HD + i);
    o.x += (float)a.x + (float)b.x;
    o.y += (float)a.y + (float)b.y;
    o.z += (float)a.z + (float)b.z;
    o.w += (float)a.w + (float)b.w;
    *(float4*)(out + (size_t)t * HD + i) = o;
  }
}

// ---------------- launcher ----------------
extern "C" void kernel_launch(void* const* d_in, const int* in_sizes, int n_in,
                              void* d_out, int out_size, void* d_ws, size_t ws_size,
                              hipStream_t stream) {
  const float* X   = (const float*)d_in[0];  // [4,4096,1024]
  const float* w1s = (const float*)d_in[1];  // [1024,4096]
  const float* w2s = (const float*)d_in[2];  // [4096,1024]
  const float* w1r = (const float*)d_in[3];  // [8,1024,4096]
  const float* w2r = (const float*)d_in[4];  // [8,4096,1024]
  const float* wr  = (const float*)d_in[5];  // [1024,8]
  float* out = (float*)d_out;                // [16777216]

  char* ws = (char*)d_ws;
  bf16* W1T       = (bf16*)(ws + 0);            // [9][4096][1024] bf16  75497472 B
  bf16* W2T       = (bf16*)(ws + 75497472);     // [9][1024][4096] bf16  75497472 B
  bf16* Xbf       = (bf16*)(ws + 150994944);    // [16384][1024] bf16    33554432 B
  int* topk_idx   = (int*)(ws + 184549376);     // 131072 B
  float* topk_w   = (float*)(ws + 184680448);   // 131072 B
  int* row_token  = (int*)(ws + 184811520);     // 204800 B
  float* row_w    = (float*)(ws + 185016320);   // 204800 B
  int* row_exp    = (int*)(ws + 185221120);     // 204800 B
  int* token_rows = (int*)(ws + 185425920);     // 131072 B
  int* meta       = (int*)(ws + 185556992);     // 256 B
  bf16* routed_out= (bf16*)(ws + 185557248);    // [34816][1024] bf16    71303168 B
  bf16* act       = (bf16*)(ws + 256860416);    // adaptive: Rc rows x 4096 bf16

  // Adaptive, EVEN chunking (256-granular). Removing the guard faulted (round 12).
  const size_t actoff = 256860416ULL;
  const size_t avail = (ws_size > actoff) ? ws_size - actoff : 0;
  long long rcmax = (long long)(avail / (ID * 2));
  if (rcmax > MAXR) rcmax = MAXR;
  rcmax &= ~255LL;
  if (rcmax < 256) rcmax = 256;  // defensive
  const int nch = (MAXR + (int)rcmax - 1) / (int)rcmax;
  const int Rc = ((MAXR / nch) + 255) & ~255;   // even chunks, <= rcmax

  cast_router_kernel<<<T_TOK / 16, 1024, 0, stream>>>(X, wr, Xbf, topk_idx, topk_w);
  transpose_cast<<<dim3(ID / 64, HD / 64, 9), 256, 0, stream>>>(w1r, w1s, W1T, HD, ID);
  transpose_cast<<<dim3(HD / 64, ID / 64, 9), 256, 0, stream>>>(w2r, w2s, W2T, ID, HD);
  scatter_kernel<<<9, 1024, 0, stream>>>(topk_idx, topk_w, row_token, row_w,
                                         row_exp, token_rows, meta);

  for (int cb = 0; cb < MAXR; cb += Rc) {
    const int ce = (cb + Rc < MAXR) ? cb + Rc : MAXR;
    // up-projection for rows [cb, ce) -> act[0 .. ce-cb)
    gemm_up<<<dim3(ID / 256, (ce - cb) / 128), 512, 0, stream>>>(
        Xbf, W1T, act, row_token, row_exp, meta, cb);
    // down-projection for rows [cb, ce): shared -> out (store), routed -> routed_out
    gemm_dn<<<dim3(HD / 256, (ce - cb) / 128), 512, 0, stream>>>(
        act, W2T, routed_out, out, row_token, row_w, row_exp, meta, cb);
  }
  combine_kernel<<<2048, 256, 0, stream>>>(out, routed_out, token_rows);
}

// Round 17
// 1193.123 us; speedup vs baseline: 1.0234x; 1.0234x over previous
//
#include <hip/hip_runtime.h>
#include <cmath>

typedef __bf16 bf16;
typedef bf16 bf16x4 __attribute__((ext_vector_type(4)));
typedef bf16 bf16x8 __attribute__((ext_vector_type(8)));
typedef float f32x4 __attribute__((ext_vector_type(4)));

#define T_TOK 16384
#define HD 1024
#define ID 4096
#define MAXR 51200          // 16384 shared + 32768 routed + 8*256 align pad

// ---------------- async global -> LDS (16B per lane, lds dest wave-uniform) ----------------
__device__ __forceinline__ void async16(const void* g, void* l) {
  void* gp = (void*)g;  // drop const
  __builtin_amdgcn_global_load_lds((__attribute__((address_space(1))) void*)gp,
                                   (__attribute__((address_space(3))) void*)l,
                                   16, 0, 0);
}

// ------- fused cast X->bf16 + router (16 tokens/block, 1024 thr; NO atomics) -------
__global__ __launch_bounds__(1024)
void cast_router_kernel(const float* __restrict__ X, const float* __restrict__ Wr,
                        bf16* __restrict__ Xb, int* __restrict__ topk_idx,
                        float* __restrict__ topk_w) {
  __shared__ float W[1024 * 9];  // pad stride 9 to dodge bank conflicts
  for (int i = threadIdx.x; i < 1024 * 8; i += 1024)
    W[(i >> 3) * 9 + (i & 7)] = Wr[i];
  __syncthreads();
  const int wave = threadIdx.x >> 6, lane = threadIdx.x & 63;
  const int t = blockIdx.x * 16 + wave;
  const float* xr = X + (size_t)t * HD;
  bf16* xb = Xb + (size_t)t * HD;
  float acc[8] = {0.f, 0.f, 0.f, 0.f, 0.f, 0.f, 0.f, 0.f};
#pragma unroll
  for (int j = 0; j < 4; ++j) {
    const int base = lane * 4 + j * 256;
    const float4 v = *(const float4*)(xr + base);
    bf16x4 o;
    o.x = (bf16)v.x; o.y = (bf16)v.y; o.z = (bf16)v.z; o.w = (bf16)v.w;
    *(bf16x4*)(xb + base) = o;
    const float xv[4] = {v.x, v.y, v.z, v.w};
#pragma unroll
    for (int c = 0; c < 4; ++c) {
      const float* wp = &W[(base + c) * 9];
#pragma unroll
      for (int e2 = 0; e2 < 8; ++e2) acc[e2] += xv[c] * wp[e2];
    }
  }
#pragma unroll
  for (int off = 32; off; off >>= 1)
#pragma unroll
    for (int e2 = 0; e2 < 8; ++e2) acc[e2] += __shfl_down(acc[e2], off);
  if (lane == 0) {
    int i0 = 0; float m0 = acc[0];
#pragma unroll
    for (int e2 = 1; e2 < 8; ++e2) if (acc[e2] > m0) { m0 = acc[e2]; i0 = e2; }
    int i1 = -1; float m1 = -3.4e38f;
#pragma unroll
    for (int e2 = 0; e2 < 8; ++e2)
      if (e2 != i0 && acc[e2] > m1) { m1 = acc[e2]; i1 = e2; }
    // renormalized top-2 softmax weights: p0/(p0+p1) = sigmoid(l0-l1)
    const float w0 = 1.f / (1.f + __expf(m1 - m0));
    topk_idx[2 * t] = i0;  topk_idx[2 * t + 1] = i1;
    topk_w[2 * t] = w0;    topk_w[2 * t + 1] = 1.f - w0;
  }
}

// ------------- transpose + cast weights: [9][R][C] f32 -> [9][C][R] bf16 -------------
__global__ __launch_bounds__(256)
void transpose_cast(const float* __restrict__ srcR, const float* __restrict__ srcS,
                    bf16* __restrict__ dst, int R, int C) {
  const int e = blockIdx.z;
  const float* src = (e < 8) ? srcR + (size_t)e * R * C : srcS;
  __shared__ float tile[64][65];
  const int c0 = blockIdx.x * 64, r0 = blockIdx.y * 64;
  const int tx = threadIdx.x & 15;   // float4 col group
  const int ty = threadIdx.x >> 4;   // row 0..15
#pragma unroll
  for (int i = 0; i < 64; i += 16) {
    const float4 v = *(const float4*)(src + (size_t)(r0 + ty + i) * C + c0 + tx * 4);
    tile[ty + i][tx * 4 + 0] = v.x;
    tile[ty + i][tx * 4 + 1] = v.y;
    tile[ty + i][tx * 4 + 2] = v.z;
    tile[ty + i][tx * 4 + 3] = v.w;
  }
  __syncthreads();
  bf16* d = dst + (size_t)e * R * C;
#pragma unroll
  for (int i = 0; i < 64; i += 16) {
    const int col = ty + i;          // src col = dst row
    bf16x4 o;
    o.x = (bf16)tile[tx * 4 + 0][col];
    o.y = (bf16)tile[tx * 4 + 1][col];
    o.z = (bf16)tile[tx * 4 + 2][col];
    o.w = (bf16)tile[tx * 4 + 3][col];
    *(bf16x4*)(d + (size_t)(c0 + col) * R + r0 + tx * 4) = o;
  }
}

// ------- stable scatter into 256-aligned per-expert segments; block 8 = shared seg -------
__global__ __launch_bounds__(1024)
void scatter_kernel(const int* __restrict__ topk_idx, const float* __restrict__ topk_w,
                    int* __restrict__ row_token, float* __restrict__ row_w,
                    int* __restrict__ row_exp, int* __restrict__ token_rows,
                    int* __restrict__ meta) {
  const int e = blockIdx.x;
  const int tid = threadIdx.x;
  const int wv = tid >> 6, ln = tid & 63;
  __shared__ int whist[16][8];
  __shared__ int hist[8];

  int lc0 = 0, lc1 = 0, lc2 = 0, lc3 = 0, lc4 = 0, lc5 = 0, lc6 = 0, lc7 = 0;
  for (int t = tid; t < T_TOK; t += 1024) {
    const int i0 = topk_idx[2 * t], i1 = topk_idx[2 * t + 1];
    lc0 += (i0 == 0) + (i1 == 0);  lc1 += (i0 == 1) + (i1 == 1);
    lc2 += (i0 == 2) + (i1 == 2);  lc3 += (i0 == 3) + (i1 == 3);
    lc4 += (i0 == 4) + (i1 == 4);  lc5 += (i0 == 5) + (i1 == 5);
    lc6 += (i0 == 6) + (i1 == 6);  lc7 += (i0 == 7) + (i1 == 7);
  }
#pragma unroll
  for (int off = 32; off; off >>= 1) {
    lc0 += __shfl_down(lc0, off); lc1 += __shfl_down(lc1, off);
    lc2 += __shfl_down(lc2, off); lc3 += __shfl_down(lc3, off);
    lc4 += __shfl_down(lc4, off); lc5 += __shfl_down(lc5, off);
    lc6 += __shfl_down(lc6, off); lc7 += __shfl_down(lc7, off);
  }
  if (ln == 0) {
    whist[wv][0] = lc0; whist[wv][1] = lc1; whist[wv][2] = lc2; whist[wv][3] = lc3;
    whist[wv][4] = lc4; whist[wv][5] = lc5; whist[wv][6] = lc6; whist[wv][7] = lc7;
  }
  __syncthreads();
  if (tid < 8) {
    int s = 0;
#pragma unroll
    for (int w = 0; w < 16; ++w) s += whist[w][tid];
    hist[tid] = s;
  }
  __syncthreads();

  if (e == 8) {  // shared-expert segment: rows [0,16384), weight 1
    for (int r = tid; r < T_TOK; r += 1024) {
      row_token[r] = r; row_w[r] = 1.f; row_exp[r] = 8;
    }
    if (tid == 0) {
      int tot = T_TOK;
      for (int i = 0; i < 8; ++i) tot += (hist[i] + 255) & ~255;
      meta[0] = tot;
    }
    return;
  }

  int base = T_TOK;
  for (int i = 0; i < e; ++i) base += (hist[i] + 255) & ~255;
  const int cnt = hist[e];
  const int pc = (cnt + 255) & ~255;

  __shared__ int wsum[16];
  int written = 0;
  for (int c = 0; c < T_TOK / 1024; ++c) {
    const int t = c * 1024 + tid;
    const int i0 = topk_idx[2 * t], i1 = topk_idx[2 * t + 1];
    const int slot = (i0 == e) ? 0 : ((i1 == e) ? 1 : -1);
    const unsigned long long m = __ballot(slot >= 0);
    if (ln == 0) wsum[wv] = (int)__popcll(m);
    __syncthreads();
    int off = written;
    for (int i = 0; i < wv; ++i) off += wsum[i];
    if (slot >= 0) {
      const int rank = (int)__popcll(m & ((1ULL << ln) - 1ULL));  // exclusive in-wave
      const int pos = base + off + rank;
      row_token[pos] = t;
      row_w[pos] = topk_w[2 * t + slot];
      row_exp[pos] = e;
      token_rows[2 * t + slot] = pos;  // inverse map for the combine pass
    }
    int tot = 0;
#pragma unroll
    for (int i = 0; i < 16; ++i) tot += wsum[i];
    written += tot;
    __syncthreads();  // wsum reused next chunk
  }
  for (int p = written + tid; p < pc; p += 1024) {  // padding rows
    row_token[base + p] = 0; row_w[base + p] = 0.f; row_exp[base + p] = e;
  }
}

// ============ UP GEMM, 256x256 tile, BK=32, 8 waves, triple-buffered (round-15) ============
// PLAIN stores (NT reverted: WRITE_SIZE showed 1.62x amplification -- NT defeats L2
// write-combining of the adjacent 32B half-lines, and forces dn to re-fetch act from HBM).
__global__ __launch_bounds__(512)
void gemm_up(const bf16* __restrict__ A0, const bf16* __restrict__ WT,
             bf16* __restrict__ bout, const int* __restrict__ row_token,
             const int* __restrict__ row_exp, const int* __restrict__ meta,
             int chunk_base) {
  constexpr int NDIM = ID, KDIM = HD;
  constexpr int NT = KDIM / 32;
  const int total = meta[0];

  const int gx = gridDim.x;
  const int nwg = gx * gridDim.y;
  int id = blockIdx.y * gx + blockIdx.x;
  {
    const int q = nwg >> 3, rm = nwg & 7;
    const int xcd = id & 7, loc = id >> 3;
    id = (xcd < rm ? xcd * (q + 1) : rm * (q + 1) + (xcd - rm) * q) + loc;
  }
  const int bx = id % gx, by = id / gx;   // by-major (bx-major measured worse, r14)

  const int r0 = chunk_base + by * 256;
  if (r0 >= total) return;
  const int n0 = bx * 256;

  __shared__ __align__(16) char lds[3 * 32768];

  const int tid = threadIdx.x;
  const int wid = tid >> 6, lane = tid & 63;
  const int e = row_exp[r0];
  const bf16* W = WT + (size_t)e * NDIM * KDIM;

  const int tr = tid >> 2;
  const int tb = tid & 3;
  const int rA0 = tr, rA1 = tr + 128;
  const int bl0 = tb ^ ((rA0 >> 1) & 3);
  const int bl1 = tb ^ ((rA1 >> 1) & 3);
  const bf16* gA0 = A0 + (size_t)row_token[r0 + rA0] * KDIM + bl0 * 8;
  const bf16* gA1 = A0 + (size_t)row_token[r0 + rA1] * KDIM + bl1 * 8;
  const bf16* gB0 = W + (size_t)(n0 + rA0) * KDIM + bl0 * 8;
  const bf16* gB1 = W + (size_t)(n0 + rA1) * KDIM + bl1 * 8;
  char* const ldsb = lds;
  const int wo = wid * 1024;

#define STAGE_A0(c, kt) async16(gA0 + (kt) * 32, ldsb + (c) * 32768 + wo)
#define STAGE_A1(c, kt) async16(gA1 + (kt) * 32, ldsb + (c) * 32768 + 8192 + wo)
#define STAGE_B0(c, kt) async16(gB0 + (kt) * 32, ldsb + (c) * 32768 + 16384 + wo)
#define STAGE_B1(c, kt) async16(gB1 + (kt) * 32, ldsb + (c) * 32768 + 24576 + wo)

  const int l15 = lane & 15, kg = lane >> 4;
  const int wr = wid >> 2, wc = wid & 3;
  int offA[8], offB[4];
#pragma unroll
  for (int m = 0; m < 8; ++m) {
    const int row = wr * 128 + m * 16 + l15;
    offA[m] = row * 64 + ((kg ^ ((row >> 1) & 3)) << 4);
  }
#pragma unroll
  for (int n = 0; n < 4; ++n) {
    const int row = wc * 64 + n * 16 + l15;
    offB[n] = 16384 + row * 64 + ((kg ^ ((row >> 1) & 3)) << 4);
  }

  f32x4 acc[8][4] = {};

  STAGE_A0(0, 0); STAGE_A1(0, 0); STAGE_B0(0, 0); STAGE_B1(0, 0);
  STAGE_A0(1, 1); STAGE_A1(1, 1); STAGE_B0(1, 1); STAGE_B1(1, 1);

  int cb = 0, cn = 2;
  for (int kt = 0; kt < NT; ++kt) {
    if (kt + 1 < NT) asm volatile("s_waitcnt vmcnt(4)" ::: "memory");
    else             asm volatile("s_waitcnt vmcnt(0)" ::: "memory");
    __builtin_amdgcn_s_barrier();
    asm volatile("" ::: "memory");
    __builtin_amdgcn_sched_barrier(0);
    const char* Tb = ldsb + cb * 32768;
    const bool pf = (kt + 2 < NT);
    const int k2 = kt + 2;
    bf16x8 bfr[4];
#pragma unroll
    for (int q = 0; q < 4; ++q) {
      if (pf) {
        if (q == 0)      STAGE_A0(cn, k2);
        else if (q == 1) STAGE_A1(cn, k2);
        else if (q == 2) STAGE_B0(cn, k2);
        else             STAGE_B1(cn, k2);
      }
      if (q == 0) {
#pragma unroll
        for (int n = 0; n < 4; ++n) bfr[n] = *(const bf16x8*)(Tb + offB[n]);
      }
      const bf16x8 a0 = *(const bf16x8*)(Tb + offA[2 * q]);
      const bf16x8 a1 = *(const bf16x8*)(Tb + offA[2 * q + 1]);
      __builtin_amdgcn_s_setprio(1);
#pragma unroll
      for (int n = 0; n < 4; ++n) {
        acc[2 * q][n] =
            __builtin_amdgcn_mfma_f32_16x16x32_bf16(a0, bfr[n], acc[2 * q][n], 0, 0, 0);
        acc[2 * q + 1][n] =
            __builtin_amdgcn_mfma_f32_16x16x32_bf16(a1, bfr[n], acc[2 * q + 1][n], 0, 0, 0);
      }
      __builtin_amdgcn_s_setprio(0);
    }
    cb = (cb == 2) ? 0 : cb + 1;
    cn = (cn == 2) ? 0 : cn + 1;
  }
#undef STAGE_A0
#undef STAGE_A1
#undef STAGE_B0
#undef STAGE_B1

  const int orow = wr * 128;
  const int ocol = n0 + wc * 64;
#pragma unroll
  for (int m = 0; m < 8; ++m) {
#pragma unroll
    for (int rr = 0; rr < 4; ++rr) {
      const int row = (r0 - chunk_base) + orow + m * 16 + kg * 4 + rr;
      bf16* p = bout + (size_t)row * NDIM + ocol + l15;
#pragma unroll
      for (int n = 0; n < 4; ++n) {
        const float x = acc[m][n][rr];
        p[n * 16] = (bf16)(x / (1.f + __expf(-x)));
      }
    }
  }
}

// ============ DOWN GEMM, 128x256 tile, BK=32, 8 waves, triple-buffered ============
__global__ __launch_bounds__(512)
void gemm_dn(const bf16* __restrict__ A0, const bf16* __restrict__ WT,
             bf16* __restrict__ bout, float* __restrict__ out,
             const int* __restrict__ row_token, const float* __restrict__ row_w,
             const int* __restrict__ row_exp, const int* __restrict__ meta,
             int chunk_base) {
  constexpr int KDIM = ID;
  constexpr int NT = KDIM / 32;  // 128
  const int total = meta[0];

  const int gx = gridDim.x;
  const int nwg = gx * gridDim.y;
  int id = blockIdx.y * gx + blockIdx.x;
  {
    const int q = nwg >> 3, rm = nwg & 7;
    const int xcd = id & 7, loc = id >> 3;
    id = (xcd < rm ? xcd * (q + 1) : rm * (q + 1) + (xcd - rm) * q) + loc;
  }
  const int bx = id % gx, by = id / gx;

  const int r0 = chunk_base + by * 128;   // 128-row tiles; segments are 256-aligned
  if (r0 >= total) return;
  const int n0 = bx * 256;

  __shared__ __align__(16) char lds[3 * 24576];  // 3 bufs x (A 8K + B 16K)

  const int tid = threadIdx.x;
  const int wid = tid >> 6, lane = tid & 63;
  const int e = row_exp[r0];
  const bf16* W = WT + (size_t)e * HD * KDIM;

  // stage units: A rows 0..127; B rows 0..127; B rows 128..255
  const int tr = tid >> 2;
  const int tb = tid & 3;
  const int bl = tb ^ ((tr >> 1) & 3);   // ((tr+128)>>1)&3 == (tr>>1)&3: same for B1
  const bf16* gA  = A0 + (size_t)(r0 - chunk_base + tr) * KDIM + bl * 8;
  const bf16* gB0 = W + (size_t)(n0 + tr) * KDIM + bl * 8;
  const bf16* gB1 = W + (size_t)(n0 + 128 + tr) * KDIM + bl * 8;
  char* const ldsb = lds;
  const int wo = wid * 1024;

#define DSTAGE_A(c, kt)  async16(gA  + (kt) * 32, ldsb + (c) * 24576 + wo)
#define DSTAGE_B0(c, kt) async16(gB0 + (kt) * 32, ldsb + (c) * 24576 + 8192 + wo)
#define DSTAGE_B1(c, kt) async16(gB1 + (kt) * 32, ldsb + (c) * 24576 + 16384 + wo)

  const int l15 = lane & 15, kg = lane >> 4;
  const int wr = wid >> 2, wc = wid & 3;  // wave grid 2(M) x 4(N); per-wave 64x64 out
  int offA[4], offB[4];
#pragma unroll
  for (int m = 0; m < 4; ++m) {
    const int row = wr * 64 + m * 16 + l15;
    offA[m] = row * 64 + ((kg ^ ((row >> 1) & 3)) << 4);
  }
#pragma unroll
  for (int n = 0; n < 4; ++n) {
    const int row = wc * 64 + n * 16 + l15;
    offB[n] = 8192 + row * 64 + ((kg ^ ((row >> 1) & 3)) << 4);
  }

  f32x4 acc[4][4] = {};

  DSTAGE_A(0, 0); DSTAGE_B0(0, 0); DSTAGE_B1(0, 0);
  DSTAGE_A(1, 1); DSTAGE_B0(1, 1); DSTAGE_B1(1, 1);

  int cb = 0, cn = 2;
  for (int kt = 0; kt < NT; ++kt) {
    if (kt + 1 < NT) asm volatile("s_waitcnt vmcnt(3)" ::: "memory");
    else             asm volatile("s_waitcnt vmcnt(0)" ::: "memory");
    __builtin_amdgcn_s_barrier();
    asm volatile("" ::: "memory");
    __builtin_amdgcn_sched_barrier(0);
    const char* Tb = ldsb + cb * 24576;
    const bool pf = (kt + 2 < NT);
    const int k2 = kt + 2;
    bf16x8 bfr[4];
#pragma unroll
    for (int q = 0; q < 4; ++q) {
      if (pf) {
        if (q == 0)      DSTAGE_A(cn, k2);
        else if (q == 1) DSTAGE_B0(cn, k2);
        else if (q == 2) DSTAGE_B1(cn, k2);
      }
      if (q == 0) {
#pragma unroll
        for (int n = 0; n < 4; ++n) bfr[n] = *(const bf16x8*)(Tb + offB[n]);
      }
      const bf16x8 a0 = *(const bf16x8*)(Tb + offA[q]);
      __builtin_amdgcn_s_setprio(1);
#pragma unroll
      for (int n = 0; n < 4; ++n)
        acc[q][n] = __builtin_amdgcn_mfma_f32_16x16x32_bf16(a0, bfr[n], acc[q][n], 0, 0, 0);
      __builtin_amdgcn_s_setprio(0);
    }
    cb = (cb == 2) ? 0 : cb + 1;
    cn = (cn == 2) ? 0 : cn + 1;
  }
#undef DSTAGE_A
#undef DSTAGE_B0
#undef DSTAGE_B1

  // epilogue. D layout (m89): col = lane&15, row = (lane>>4)*4 + reg
  const int orow = wr * 64;
  const int ocol = n0 + wc * 64;
  if (e == 8) {
#pragma unroll
    for (int m = 0; m < 4; ++m) {
#pragma unroll
      for (int rr = 0; rr < 4; ++rr) {
        const int row = r0 + orow + m * 16 + kg * 4 + rr;
        const int tok = row_token[row];
        float* p = out + (size_t)tok * HD + ocol + l15;
#pragma unroll
        for (int n = 0; n < 4; ++n) p[n * 16] = acc[m][n][rr];
      }
    }
  } else {
#pragma unroll
    for (int m = 0; m < 4; ++m) {
#pragma unroll
      for (int rr = 0; rr < 4; ++rr) {
        const int row = r0 + orow + m * 16 + kg * 4 + rr;
        const float w = row_w[row];
        bf16* p = bout + (size_t)(row - T_TOK) * HD + ocol + l15;
#pragma unroll
        for (int n = 0; n < 4; ++n)
          p[n * 16] = (bf16)(w * acc[m][n][rr]);
      }
    }
  }
}

// -------- combine: out[t] += routed_out[rowA(t)] + routed_out[rowB(t)] (grid-stride) --------
__global__ __launch_bounds__(256)
void combine_kernel(float* __restrict__ out, const bf16* __restrict__ routed_out,
                    const int* __restrict__ token_rows) {
  const int i = (threadIdx.x & 255) * 4;
  for (int t = blockIdx.x; t < T_TOK; t += gridDim.x) {
    const int rA = token_rows[2 * t] - T_TOK;
    const int rB = token_rows[2 * t + 1] - T_TOK;
    float4 o = *(const float4*)(out + (size_t)t * HD + i);
    const bf16x4 a = *(const bf16x4*)(routed_out + (size_t)rA * HD + i);
    const bf16x4 b = *(const bf16x4*)(routed_out + (size_t)rB * HD + i);
    o.x += (float)a.x + (float)b.x;
    o.y += (float)a.y + (float)b.y;
    o.z += (float)a.z + (float)b.z;
    o.w += (float)a.w + (float)b.w;
    *(float4*)(out + (size_t)t * HD + i) = o;
  }
}

// ---------------- launcher ----------------
extern "C" void kernel_launch(void* const* d_in, const int* in_sizes, int n_in,
                              void* d_out, int out_size, void* d_ws, size_t ws_size,
                              hipStream_t stream) {
  const float* X   = (const float*)d_in[0];  // [4,4096,1024]
  const float* w1s = (const float*)d_in[1];  // [1024,4096]
  const float* w2s = (const float*)d_in[2];  // [4096,1024]
  const float* w1r = (const float*)d_in[3];  // [8,1024,4096]
  const float* w2r = (const float*)d_in[4];  // [8,4096,1024]
  const float* wr  = (const float*)d_in[5];  // [1024,8]
  float* out = (float*)d_out;                // [16777216]

  char* ws = (char*)d_ws;
  bf16* W1T       = (bf16*)(ws + 0);            // [9][4096][1024] bf16  75497472 B
  bf16* W2T       = (bf16*)(ws + 75497472);     // [9][1024][4096] bf16  75497472 B
  bf16* Xbf       = (bf16*)(ws + 150994944);    // [16384][1024] bf16    33554432 B
  int* topk_idx   = (int*)(ws + 184549376);     // 131072 B
  float* topk_w   = (float*)(ws + 184680448);   // 131072 B
  int* row_token  = (int*)(ws + 184811520);     // 204800 B
  float* row_w    = (float*)(ws + 185016320);   // 204800 B
  int* row_exp    = (int*)(ws + 185221120);     // 204800 B
  int* token_rows = (int*)(ws + 185425920);     // 131072 B
  int* meta       = (int*)(ws + 185556992);     // 256 B
  bf16* routed_out= (bf16*)(ws + 185557248);    // [34816][1024] bf16    71303168 B
  bf16* act       = (bf16*)(ws + 256860416);    // adaptive: Rc rows x 4096 bf16

  // Adaptive, EVEN chunking (256-granular). Removing the guard faulted (round 12).
  const size_t actoff = 256860416ULL;
  const size_t avail = (ws_size > actoff) ? ws_size - actoff : 0;
  long long rcmax = (long long)(avail / (ID * 2));
  if (rcmax > MAXR) rcmax = MAXR;
  rcmax &= ~255LL;
  if (rcmax < 256) rcmax = 256;  // defensive
  const int nch = (MAXR + (int)rcmax - 1) / (int)rcmax;
  const int Rc = ((MAXR / nch) + 255) & ~255;   // even chunks, <= rcmax

  cast_router_kernel<<<T_TOK / 16, 1024, 0, stream>>>(X, wr, Xbf, topk_idx, topk_w);
  transpose_cast<<<dim3(ID / 64, HD / 64, 9), 256, 0, stream>>>(w1r, w1s, W1T, HD, ID);
  transpose_cast<<<dim3(HD / 64, ID / 64, 9), 256, 0, stream>>>(w2r, w2s, W2T, ID, HD);
  scatter_kernel<<<9, 1024, 0, stream>>>(topk_idx, topk_w, row_token, row_w,
                                         row_exp, token_rows, meta);

  for (int cb = 0; cb < MAXR; cb += Rc) {
    const int ce = (cb + Rc < MAXR) ? cb + Rc : MAXR;
    // up-projection for rows [cb, ce) -> act[0 .. ce-cb)
    gemm_up<<<dim3(ID / 256, (ce - cb) / 256), 512, 0, stream>>>(
        Xbf, W1T, act, row_token, row_exp, meta, cb);
    // down-projection for rows [cb, ce): shared -> out (store), routed -> routed_out
    gemm_dn<<<dim3(HD / 256, (ce - cb) / 128), 512, 0, stream>>>(
        act, W2T, routed_out, out, row_token, row_w, row_exp, meta, cb);
  }
  combine_kernel<<<2048, 256, 0, stream>>>(out, routed_out, token_rows);
}